// Round 11
// baseline (13919.191 us; speedup 1.0000x reference)
//
#include <hip/hip_runtime.h>
#include <hip/hip_cooperative_groups.h>

namespace cg = cooperative_groups;

#define NN 2048
#define NB 32
#define NT 500
#define WGS 1024
#define NWG 256

// Persistent cooperative kernel. R11 = R10's light sync (8 padded cumulative
// counters, 4 polling threads/WG, coherent VECTOR payload) + R8's record path
// (LDS-staged NONTEMPORAL stores -- R10's plain scatter stores caused 3 GB of
// L2-thrash/RMW refetch) + R8's occupancy (1024 thr, 2 rows/thread, 16
// waves/CU). No cache-invalidating fences (R4 lesson). Atomic volume stays
// ~1K ops/step (vs R8's 262K).
//
// Safety: cnt[p][w] cumulative, +256/round; WG reaches step s's poll only
// after publishing s, so cnt[p]==256k implies all WGs finished reading
// buf[p^1] for s-1 -> overwriting buf[p^1] with s+1 is safe. Replay-safe:
// counters re-zeroed in init before one cg grid.sync; step 0 skips exchange.
//
// Compute body == R7/R8 (validated): WG owns 8 rows; thread (rh,jh,b) does
// 2 rows x 256-consecutive-j sequential chunk (x,y,z,w bit order); chunks
// combined 0..7 in order by the (row,b) owner. Bit-exact order preserved.
//
// ws: buf u64[2][1024] @0 (16 KB) | cnt u32[2*4*32] @16384 (1 KB) |
//     xT f32[500][32] @17408 | wgpart i32[256] @81408

__device__ __forceinline__ unsigned long long load_coh8(const void* p) {
    unsigned long long v;
    asm volatile("global_load_dwordx2 %0, %1, off sc0 sc1\n\t"
                 "s_waitcnt vmcnt(0)"
                 : "=&v"(v) : "v"(p) : "memory");
    return v;
}

__device__ __forceinline__ void store_coh8(void* p, unsigned long long v) {
    asm volatile("global_store_dwordx2 %0, %1, off sc0 sc1"
                 :: "v"(p), "v"(v) : "memory");
}

__launch_bounds__(WGS, 4)
__global__ void reservoir_kernel(const float* __restrict__ x,
                                 const float* __restrict__ W,
                                 const float* __restrict__ bias,
                                 float* __restrict__ out,
                                 void* __restrict__ wsv)
{
    cg::grid_group grid = cg::this_grid();

    __shared__ unsigned int lbits[NN];      // 8 KB spike bits
    __shared__ float lpart[8][8][32];       // 8 KB [jh][row][b]
    __shared__ float lout[2][NB][9];        // padded output stage
    __shared__ int   lcnt[4];

    unsigned long long* buf = (unsigned long long*)wsv;              // [2][1024]
    unsigned int* cnt       = (unsigned int*)((char*)wsv + 16384);   // [2*4*32]
    float* xT               = (float*)((char*)wsv + 17408);          // [500][32]
    int*   wgpart           = (int*)((char*)wsv + 81408);            // [256]

    const int wg = blockIdx.x;
    const int t  = threadIdx.x;
    const int i0 = wg * 8;

    // init: counters zeroed (replay safety), x transposed to xT[step][b]
    if (wg == 0 && t < 8)
        __hip_atomic_store(&cnt[t * 32], 0u,
                           __ATOMIC_RELAXED, __HIP_MEMORY_SCOPE_AGENT);
    for (int g = wg * WGS + t; g < NT * NB; g += NWG * WGS)
        xT[g] = x[(size_t)(g & 31) * NT + (g >> 5)];

    // compute identity (== R7/R8): 2 rows per thread
    const int rh = t >> 8;          // 0..3 -> rows 2rh, 2rh+1
    const int jh = (t >> 5) & 7;    // chunk 0..7
    const int b  = t & 31;          // batch

    const float4* __restrict__ wr0 = (const float4*)(W + (size_t)(i0 + 2 * rh    ) * NN) + jh * 64;
    const float4* __restrict__ wr1 = (const float4*)(W + (size_t)(i0 + 2 * rh + 1) * NN) + jh * 64;

    // combine identity (t < 256): (row cil, batch cb), state in registers
    const int cil = t >> 5;
    const int cb  = t & 31;
    const float biasv = (t < 256) ? bias[i0 + cil] : 0.0f;
    float mem = 0.0f;
    int   scount = 0;

    float* spk_rec = out + 1;
    float* mem_rec = out + 1 + (size_t)NT * NB * NN;

    grid.sync();   // init visibility (once)

    unsigned int tgt0 = 0, tgt1 = 0;

    for (int step = 0; step < NT; ++step) {
        const int pcur = step & 1;

        if (step == 0) {
            // spikes known all-zero: no exchange
            ((uint2*)lbits)[t] = make_uint2(0u, 0u);
        } else {
            if (pcur) tgt1 += 256; else tgt0 += 256;
            const unsigned int tg = pcur ? tgt1 : tgt0;
            if (t < 4) {
                while (__hip_atomic_load(&cnt[(pcur * 4 + t) * 32], __ATOMIC_RELAXED,
                                         __HIP_MEMORY_SCOPE_AGENT) < tg)
                    __builtin_amdgcn_s_sleep(1);
            }
            __syncthreads();   // (B0) data ready grid-wide

            unsigned long long v =
                load_coh8((const char*)(buf + (size_t)pcur * 1024) + 8 * t);
            *(unsigned long long*)&lbits[2 * t] = v;
        }
        const float xv = (t < 256) ? xT[step * NB + cb] : 0.0f;
        __syncthreads();   // (B) lbits staged

        // chunk partial: 2 rows x 1 batch over 256 consecutive j (bit-exact order)
        float c0 = 0.0f, c1 = 0.0f;
        const uint4* bp = ((const uint4*)lbits) + jh * 64;
        #pragma unroll 4
        for (int jj = 0; jj < 64; ++jj) {
            const float4 w0 = wr0[jj];
            const float4 w1 = wr1[jj];
            const uint4  bu = bp[jj];
            float s;
            s = (float)((bu.x >> b) & 1u); c0 = fmaf(w0.x, s, c0); c1 = fmaf(w1.x, s, c1);
            s = (float)((bu.y >> b) & 1u); c0 = fmaf(w0.y, s, c0); c1 = fmaf(w1.y, s, c1);
            s = (float)((bu.z >> b) & 1u); c0 = fmaf(w0.z, s, c0); c1 = fmaf(w1.z, s, c1);
            s = (float)((bu.w >> b) & 1u); c0 = fmaf(w0.w, s, c0); c1 = fmaf(w1.w, s, c1);
        }
        lpart[jh][2 * rh    ][b] = c0;
        lpart[jh][2 * rh + 1][b] = c1;
        __syncthreads();   // (C) lpart ready

        if (t < 256) {
            // sequential combine over chunks (bit-exact validated order)
            float d = lpart[0][cil][cb];
            #pragma unroll
            for (int k = 1; k < 8; ++k) d += lpart[k][cil][cb];

            const float sp = (float)((lbits[i0 + cil] >> cb) & 1u);

            float base = 0.95f * mem + xv + d + biasv;
            float nm   = base * (1.0f - sp);
            float ns   = (nm > 1.0f) ? 1.0f : 0.0f;
            mem = nm;
            scount += (int)ns;

            // publish: one coherent 8B store per wave -> vmcnt -> one atomicAdd
            unsigned long long bal = __ballot(ns > 0.5f);  // lo32=row 2w2, hi32=row 2w2+1
            const int l  = t & 63;
            const int w2 = t >> 6;
            const int pnxt = pcur ^ 1;
            if (l == 0)
                store_coh8((char*)(buf + (size_t)pnxt * 1024) + 8 * (4 * wg + w2), bal);
            asm volatile("s_waitcnt vmcnt(0)" ::: "memory");
            if (l == 0)
                __hip_atomic_fetch_add(&cnt[(pnxt * 4 + w2) * 32], 1u,
                                       __ATOMIC_RELAXED, __HIP_MEMORY_SCOPE_AGENT);

            lout[0][cb][cil] = ns;
            lout[1][cb][cil] = nm;
        }
        __syncthreads();   // (D) lout staged

        // record stores: LDS-staged, nontemporal (keeps W in L2 -- R10 lesson)
        if (t < 512) {
            const int arr = t >> 8;
            const int r2  = t & 255;
            const int bb  = r2 >> 3;
            const int il  = r2 & 7;
            size_t o = ((size_t)step * NB + bb) * (size_t)NN + i0 + il;
            if (arr == 0) __builtin_nontemporal_store(lout[0][bb][il], &spk_rec[o]);
            else          __builtin_nontemporal_store(lout[1][bb][il], &mem_rec[o]);
        }
    }

    // average firing rate (scount==0 for t>=256)
    #pragma unroll
    for (int d2 = 1; d2 < 64; d2 <<= 1) scount += __shfl_xor(scount, d2, 64);
    if ((t & 63) == 0 && t < 256) lcnt[t >> 6] = scount;
    __syncthreads();
    if (t == 0) wgpart[wg] = lcnt[0] + lcnt[1] + lcnt[2] + lcnt[3];
    grid.sync();
    if (wg == 0) {
        int ps = (t < NWG) ? wgpart[t] : 0;
        #pragma unroll
        for (int d2 = 1; d2 < 64; d2 <<= 1) ps += __shfl_xor(ps, d2, 64);
        if ((t & 63) == 0 && t < 256) lcnt[t >> 6] = ps;
        __syncthreads();
        if (t == 0) {
            long long s2 = (long long)lcnt[0] + lcnt[1] + lcnt[2] + lcnt[3];
            out[0] = (float)((double)s2 / (double)((long long)NT * NB * NN));
        }
    }
}

extern "C" void kernel_launch(void* const* d_in, const int* in_sizes, int n_in,
                              void* d_out, int out_size, void* d_ws, size_t ws_size,
                              hipStream_t stream) {
    const float* x    = (const float*)d_in[0];  // (32, 500, 1)
    const float* W    = (const float*)d_in[1];  // (2048, 2048)
    const float* bias = (const float*)d_in[2];  // (2048,)
    float* out = (float*)d_out;
    void*  ws  = d_ws;

    void* args[] = { (void*)&x, (void*)&W, (void*)&bias, (void*)&out, (void*)&ws };
    hipLaunchCooperativeKernel((const void*)reservoir_kernel,
                               dim3(NWG), dim3(WGS), args, 0, stream);
}

// Round 13
// 9784.528 us; speedup vs baseline: 1.4226x; 1.4226x over previous
//
#include <hip/hip_runtime.h>
#include <hip/hip_cooperative_groups.h>

namespace cg = cooperative_groups;

#define NN 2048
#define NB 32
#define NT 500
#define WGS 1024
#define NWG 256

// Persistent cooperative kernel, TWO INDEPENDENT BATCH GROUPS.
//  group g = wg>>7 owns batches 16g..16g+15; row_block rb = wg&127 owns rows
//  16rb..16rb+15. Groups never communicate until the final reduction -> each
//  per-step exchange has only 128 participants, and the two groups drift
//  independently (straggler decoupling). W locality: wg and wg+128 own the
//  same 16 W rows and (round-robin placement) the same XCD -> shared L2 lines.
//
// Exchange per group == R8's validated mechanism: producer wave publishes one
// u64 ballot (4 rows x 16 batches) with a coherent store -> vmcnt -> epoch
// store; consumers poll their own epoch word then bulk-load the payload with
// an atomic u64 load. No cache-invalidating fences (R4 lesson), no leaders,
// no placement assumptions for correctness (R12 lesson). Replay-safe: epochs
// re-zeroed in init before one cg grid.sync; step 0 skips the exchange.
//
// Per-(i,b) summation order == R3..R11 (validated): 8 chunks of 256
// consecutive j, sequential fma over x,y,z,w within each float4, chunks
// combined 0..7 in order by the single (row,b) owner thread. Bit-exact.
//
// ws: data64 u64[2grp][2par][512] @0 (16 KB) | ep u32[2][512] @16384 (4 KB) |
//     xT f32[500][32] @20480 (64 KB) | wgpart i32[256] @84480

__device__ __forceinline__ void store_coh8(void* p, unsigned long long v) {
    asm volatile("global_store_dwordx2 %0, %1, off sc0 sc1"
                 :: "v"(p), "v"(v) : "memory");
}

__launch_bounds__(WGS, 4)
__global__ void reservoir_kernel(const float* __restrict__ x,
                                 const float* __restrict__ W,
                                 const float* __restrict__ bias,
                                 float* __restrict__ out,
                                 void* __restrict__ wsv)
{
    cg::grid_group grid = cg::this_grid();

    __shared__ unsigned short lb16[NN];     // 4 KB: 2048 rows x 16 batch-bits
    __shared__ float lpart[8][16][16];      // 16 KB [jh][row][b]
    __shared__ float lout[2][16][17];       // padded output stage
    __shared__ int   lcnt[4];

    unsigned long long* data64 = (unsigned long long*)wsv;           // [2][2][512]
    unsigned int* ep  = (unsigned int*)((char*)wsv + 16384);         // [2][512]
    float* xT         = (float*)((char*)wsv + 20480);                // [500][32]
    int*   wgpart     = (int*)((char*)wsv + 84480);                  // [256]

    const int wg  = blockIdx.x;
    const int t   = threadIdx.x;
    const int rb  = wg & 127;      // row block
    const int grp = wg >> 7;       // batch group
    const int i0  = rb * 16;
    const int b0  = grp * 16;

    // init: zero both groups' epochs (replay safety); transpose x
    if (wg == 0)
        __hip_atomic_store(&ep[t], 0u, __ATOMIC_RELAXED, __HIP_MEMORY_SCOPE_AGENT);
    for (int g = wg * WGS + t; g < NT * NB; g += NWG * WGS)
        xT[g] = x[(size_t)(g & 31) * NT + (g >> 5)];

    // compute identity: 2 rows x 1 batch x 256-j chunk per thread
    const int rh = t >> 7;          // 0..7 -> rows 2rh, 2rh+1
    const int jh = (t >> 4) & 7;    // chunk 0..7
    const int b  = t & 15;          // batch within group

    const float4* __restrict__ wr0 = (const float4*)(W + (size_t)(i0 + 2 * rh    ) * NN) + jh * 64;
    const float4* __restrict__ wr1 = (const float4*)(W + (size_t)(i0 + 2 * rh + 1) * NN) + jh * 64;

    // combine identity (t < 256): row cil (16), batch cb (16)
    const int cil = t >> 4;
    const int cb  = t & 15;
    const float biasv = (t < 256) ? bias[i0 + cil] : 0.0f;
    float mem = 0.0f;
    int   scount = 0;

    float* spk_rec = out + 1;
    float* mem_rec = out + 1 + (size_t)NT * NB * NN;

    unsigned int* epg = ep + grp * 512;
    unsigned long long* dgrp = data64 + (size_t)grp * 1024;   // [2][512]

    grid.sync();   // init visibility (once)

    for (int step = 0; step < NT; ++step) {
        const int pcur = step & 1;

        if (step == 0) {
            if (t < 512) ((unsigned long long*)lb16)[t] = 0ull;
        } else if (t < 512) {
            // poll own producer epoch (4B), then one atomic u64 payload load
            while (__hip_atomic_load(&epg[t], __ATOMIC_RELAXED,
                                     __HIP_MEMORY_SCOPE_AGENT) < (unsigned int)step)
                __builtin_amdgcn_s_sleep(1);
            unsigned long long v =
                __hip_atomic_load(&dgrp[(size_t)pcur * 512 + t],
                                  __ATOMIC_RELAXED, __HIP_MEMORY_SCOPE_AGENT);
            ((unsigned long long*)lb16)[t] = v;   // word w -> rows 4w..4w+3
        }
        const float xv = (t < 256) ? xT[step * NB + b0 + cb] : 0.0f;
        __syncthreads();   // (B) lb16 staged

        // chunk partial: 2 rows x 1 batch over 256 consecutive j (bit-exact order)
        float c0 = 0.0f, c1 = 0.0f;
        const uint2* bp = ((const uint2*)lb16) + jh * 64;
        #pragma unroll 4
        for (int jj = 0; jj < 64; ++jj) {
            const float4 w0 = wr0[jj];
            const float4 w1 = wr1[jj];
            const uint2  bu = bp[jj];    // 4 x u16 spike masks (j..j+3)
            float s;
            s = (float)((bu.x >> b) & 1u);        c0 = fmaf(w0.x, s, c0); c1 = fmaf(w1.x, s, c1);
            s = (float)((bu.x >> (16 + b)) & 1u); c0 = fmaf(w0.y, s, c0); c1 = fmaf(w1.y, s, c1);
            s = (float)((bu.y >> b) & 1u);        c0 = fmaf(w0.z, s, c0); c1 = fmaf(w1.z, s, c1);
            s = (float)((bu.y >> (16 + b)) & 1u); c0 = fmaf(w0.w, s, c0); c1 = fmaf(w1.w, s, c1);
        }
        lpart[jh][2 * rh    ][b] = c0;
        lpart[jh][2 * rh + 1][b] = c1;
        __syncthreads();   // (C) lpart ready

        if (t < 256) {
            // sequential combine over chunks (bit-exact validated order)
            float d = lpart[0][cil][cb];
            #pragma unroll
            for (int k = 1; k < 8; ++k) d += lpart[k][cil][cb];

            const float sp = (float)((lb16[i0 + cil] >> cb) & 1u);

            float base = 0.95f * mem + xv + d + biasv;
            float nm   = base * (1.0f - sp);
            float ns   = (nm > 1.0f) ? 1.0f : 0.0f;
            mem = nm;
            scount += (int)ns;

            // publish: wave ballot (4 rows x 16 b) -> coherent store -> vmcnt -> epoch
            unsigned long long bal = __ballot(ns > 0.5f);
            const int l  = t & 63;
            const int w2 = t >> 6;
            const int pnxt = pcur ^ 1;
            if (l == 0)
                store_coh8(&dgrp[(size_t)pnxt * 512 + 4 * rb + w2], bal);
            asm volatile("s_waitcnt vmcnt(0)" ::: "memory");
            if (l == 0)
                __hip_atomic_store(&epg[4 * rb + w2], (unsigned int)(step + 1),
                                   __ATOMIC_RELAXED, __HIP_MEMORY_SCOPE_AGENT);

            lout[0][cb][cil] = ns;
            lout[1][cb][cil] = nm;
        }
        __syncthreads();   // (D) lout staged

        // record stores: LDS-staged, nontemporal, 64B row-runs (R10 lesson)
        if (t < 512) {
            const int arr = t >> 8;
            const int r2  = t & 255;
            const int bb  = r2 >> 4;
            const int il  = r2 & 15;
            size_t o = ((size_t)step * NB + (b0 + bb)) * (size_t)NN + i0 + il;
            if (arr == 0) __builtin_nontemporal_store(lout[0][bb][il], &spk_rec[o]);
            else          __builtin_nontemporal_store(lout[1][bb][il], &mem_rec[o]);
        }
    }

    // average firing rate (scount==0 for t>=256)
    #pragma unroll
    for (int d2 = 1; d2 < 64; d2 <<= 1) scount += __shfl_xor(scount, d2, 64);
    if ((t & 63) == 0 && t < 256) lcnt[t >> 6] = scount;
    __syncthreads();
    if (t == 0) wgpart[wg] = lcnt[0] + lcnt[1] + lcnt[2] + lcnt[3];
    grid.sync();
    if (wg == 0) {
        int ps = (t < NWG) ? wgpart[t] : 0;
        #pragma unroll
        for (int d2 = 1; d2 < 64; d2 <<= 1) ps += __shfl_xor(ps, d2, 64);
        if ((t & 63) == 0 && t < 256) lcnt[t >> 6] = ps;
        __syncthreads();
        if (t == 0) {
            long long s2 = (long long)lcnt[0] + lcnt[1] + lcnt[2] + lcnt[3];
            out[0] = (float)((double)s2 / (double)((long long)NT * NB * NN));
        }
    }
}

extern "C" void kernel_launch(void* const* d_in, const int* in_sizes, int n_in,
                              void* d_out, int out_size, void* d_ws, size_t ws_size,
                              hipStream_t stream) {
    const float* x    = (const float*)d_in[0];  // (32, 500, 1)
    const float* W    = (const float*)d_in[1];  // (2048, 2048)
    const float* bias = (const float*)d_in[2];  // (2048,)
    float* out = (float*)d_out;
    void*  ws  = d_ws;

    void* args[] = { (void*)&x, (void*)&W, (void*)&bias, (void*)&out, (void*)&ws };
    hipLaunchCooperativeKernel((const void*)reservoir_kernel,
                               dim3(NWG), dim3(WGS), args, 0, stream);
}